// Round 3
// baseline (1247.678 us; speedup 1.0000x reference)
//
#include <hip/hip_runtime.h>
#include <math.h>

#define NEGV -9000000000000000.0f

__device__ __forceinline__ float wave_sum(float v) {
#pragma unroll
  for (int m = 32; m; m >>= 1) v += __shfl_xor(v, m, 64);
  return v;
}

// Stage src[0..63] into this wave's private LDS buffer (wave-local ordering).
__device__ __forceinline__ void wave_stage(float* xbuf, int lane,
                                           const float* __restrict__ src) {
  __builtin_amdgcn_wave_barrier();
  xbuf[lane] = src[lane];
  __builtin_amdgcn_wave_barrier();
  asm volatile("s_waitcnt lgkmcnt(0)" ::: "memory");
  __builtin_amdgcn_wave_barrier();
}

// y_e = sum_d W[r][e=lane][d] * x[d]; sequential-d fmaf chain (bit-exact order).
__device__ __forceinline__ float dotrow(const float* __restrict__ W, int r, int lane,
                                        const float* xbuf) {
  const float* Wr = W + (((size_t)r) << 12) + ((size_t)lane << 6);
  float acc = 0.f;
#pragma unroll
  for (int i = 0; i < 16; ++i) {
    float4 w = *(const float4*)(Wr + 4 * i);
    float4 x = *(const float4*)(xbuf + 4 * i);
    acc = fmaf(w.x, x.x, acc);
    acc = fmaf(w.y, x.y, acc);
    acc = fmaf(w.z, x.z, acc);
    acc = fmaf(w.w, x.w, acc);
  }
  return acc;
}

__device__ __forceinline__ float transform_one(int nb, int r, int lane,
                                               const float* __restrict__ emb,
                                               const float* __restrict__ W, float* xbuf) {
  wave_stage(xbuf, lane, emb + ((size_t)nb << 6));
  return tanhf(dotrow(W, r, lane, xbuf));
}

// ---- user embedding: 4 waves/block, wave = one batch element ----
__global__ __launch_bounds__(256) void k_user(const int* __restrict__ ui,
                                              const float* __restrict__ emb,
                                              const int* __restrict__ clicked,
                                              const float* __restrict__ numc, int hist,
                                              float* __restrict__ user_emb, int ntask) {
  int w = threadIdx.x >> 6, lane = threadIdx.x & 63;
  int b = blockIdx.x * 4 + w;
  if (b >= ntask) return;
  int u = ui[b];
  float acc = 0.f;
  for (int h = 0; h < hist; ++h) {
    int it = clicked[u * hist + h];
    acc += emb[((size_t)it << 6) + lane];
  }
  user_emb[((size_t)b << 6) + lane] = acc * (1.0f / numc[u]);
}

// ---- score: one wave per (task, neighbor). Fully parallel. ----
__global__ __launch_bounds__(256) void k_score(
    const int* __restrict__ eid_list, int shift, const float* __restrict__ emb,
    const float* __restrict__ W, const int* __restrict__ adjE,
    const int* __restrict__ adjR, const float* __restrict__ user_emb,
    float* __restrict__ sbuf, int nwave) {
  __shared__ __align__(16) float xb[4][64];
  int w = threadIdx.x >> 6, lane = threadIdx.x & 63;
  int gw = blockIdx.x * 4 + w;
  if (gw >= nwave) return;
  int t = gw >> 6, n = gw & 63;
  int eid = eid_list[t];
  int b = t >> shift;
  int nb = adjE[((size_t)eid << 6) + n];
  int r = adjR[((size_t)eid << 6) + n];
  float u_e = user_emb[((size_t)b << 6) + lane];
  float y = transform_one(nb, r, lane, emb, W, xb[w]);
  float tot = wave_sum(u_e * y);
  if (lane == 0) sbuf[gw] = tot * (1.0f / 64.0f);
}

// ---- topsel: one wave per task: masked softmax, top-8 (value desc, index asc),
//      second masked softmax; emit selected (entity, rel, weight). ----
__global__ __launch_bounds__(256) void k_topsel(const int* __restrict__ eid_list,
                                                const int* __restrict__ adjE,
                                                const int* __restrict__ adjR,
                                                const float* __restrict__ sbuf,
                                                int* __restrict__ e_sel,
                                                int* __restrict__ r_sel,
                                                float* __restrict__ wgt, int ntask) {
  int w = threadIdx.x >> 6, lane = threadIdx.x & 63;
  int t = blockIdx.x * 4 + w;
  if (t >= ntask) return;
  int eid = eid_list[t];
  float s_mine = sbuf[((size_t)t << 6) + lane];
  // masked softmax over 64 neighbors
  float sv = (s_mine == 0.0f) ? NEGV : s_mine;
  float mx = sv;
#pragma unroll
  for (int m = 32; m; m >>= 1) mx = fmaxf(mx, __shfl_xor(mx, m, 64));
  float p = expf(sv - mx);
  float Z = wave_sum(p);
  p /= Z;
  // top-8: iterative butterfly argmax with (value desc, index asc)
  float v = p;
  int vi = lane;
  float selv[8];
  int seli[8];
#pragma unroll
  for (int j = 0; j < 8; ++j) {
    float bv = v;
    int bi = vi;
#pragma unroll
    for (int m = 1; m < 64; m <<= 1) {
      float ov = __shfl_xor(bv, m, 64);
      int oi = __shfl_xor(bi, m, 64);
      if (ov > bv || (ov == bv && oi < bi)) { bv = ov; bi = oi; }
    }
    selv[j] = bv;
    seli[j] = bi;
    if (lane == bi) v = -__builtin_inff();
  }
  // second masked softmax over the 8 selected
  float m8 = -__builtin_inff();
#pragma unroll
  for (int j = 0; j < 8; ++j) {
    float tt = (selv[j] == 0.f) ? NEGV : selv[j];
    selv[j] = tt;
    m8 = fmaxf(m8, tt);
  }
  float Z8 = 0.f;
#pragma unroll
  for (int j = 0; j < 8; ++j) {
    selv[j] = expf(selv[j] - m8);
    Z8 += selv[j];
  }
  int nbr = adjE[((size_t)eid << 6) + lane];
  int rel = adjR[((size_t)eid << 6) + lane];
#pragma unroll
  for (int j = 0; j < 8; ++j) {
    int nb = __shfl(nbr, seli[j], 64);
    int rr = __shfl(rel, seli[j], 64);
    if (lane == 0) {
      e_sel[t * 8 + j] = nb;
      r_sel[t * 8 + j] = rr;
      wgt[t * 8 + j] = selv[j] / Z8;
    }
  }
}

// ---- transform selected entities: one wave per selected slot ----
__global__ __launch_bounds__(256) void k_transform(const int* __restrict__ e_sel,
                                                   const int* __restrict__ r_sel,
                                                   const float* __restrict__ emb,
                                                   const float* __restrict__ W,
                                                   float* __restrict__ out, int nwave) {
  __shared__ __align__(16) float xb[4][64];
  int w = threadIdx.x >> 6, lane = threadIdx.x & 63;
  int gw = blockIdx.x * 4 + w;
  if (gw >= nwave) return;
  float y = transform_one(e_sel[gw], r_sel[gw], lane, emb, W, xb[w]);
  out[((size_t)gw << 6) + lane] = y;
}

// ---- hop1 aggregation (emb + labels), one wave per (b,j) ----
__global__ __launch_bounds__(256) void k_agg1(
    const int* __restrict__ ui, const int* __restrict__ ii, const float* __restrict__ emb,
    const float* __restrict__ W, const float* __restrict__ labels, int np1,
    const int* __restrict__ e1, const int* __restrict__ e2, const int* __restrict__ r2,
    const float* __restrict__ w1, const float* __restrict__ emb1,
    float* __restrict__ emb1p, float* __restrict__ lab1p, int ntask) {
  __shared__ __align__(16) float xb[4][64];
  int w = threadIdx.x >> 6, lane = threadIdx.x & 63;
  int bj = blockIdx.x * 4 + w;
  if (bj >= ntask) return;
  float* xbuf = xb[w];
  int b = bj >> 3;
  int u = ui[b];
  int item = ii[b];
  int eid = e1[bj];
  float agg = 0.f, labagg = 0.f;
#pragma unroll
  for (int k = 0; k < 8; ++k) {
    int nb = e2[bj * 8 + k];
    int r = r2[bj * 8 + k];
    float wk = w1[bj * 8 + k];
    float y = transform_one(nb, r, lane, emb, W, xbuf);
    agg = fmaf(wk, y, agg);
    float raw2 = labels[(size_t)u * np1 + nb];
    float lab2 = (nb != item) ? raw2 : 0.5f;
    labagg = fmaf(wk, lab2, labagg);
  }
  float base = emb1[((size_t)bj << 6) + lane];
  emb1p[((size_t)bj << 6) + lane] = fmaxf(fmaf(agg, 0.125f, base), 0.f);
  if (lane == 0) {
    float raw1 = labels[(size_t)u * np1 + eid];
    bool hm = (eid != item);
    float l1 = hm ? raw1 : 0.5f;
    bool reset1 = (raw1 != 0.5f) && hm;
    lab1p[bj] = reset1 ? l1 : labagg;
  }
}

__global__ __launch_bounds__(256) void k_final(const int* __restrict__ ii,
                                               const float* __restrict__ emb,
                                               const float* __restrict__ user_emb,
                                               const float* __restrict__ s0,
                                               const float* __restrict__ emb1,
                                               const float* __restrict__ emb1p,
                                               const float* __restrict__ lab1p,
                                               float* __restrict__ out, int bs) {
  int w = threadIdx.x >> 6, lane = threadIdx.x & 63;
  int b = blockIdx.x * 4 + w;
  if (b >= bs) return;
  int item = ii[b];
  float ue = user_emb[((size_t)b << 6) + lane];
  float agg = 0.f, aggp = 0.f, lab = 0.f;
#pragma unroll
  for (int j = 0; j < 8; ++j) {
    float s = s0[b * 8 + j];
    agg = fmaf(s, emb1[(((size_t)b * 8 + j) << 6) + lane], agg);
    aggp = fmaf(s, emb1p[(((size_t)b * 8 + j) << 6) + lane], aggp);
    lab = fmaf(s, lab1p[b * 8 + j], lab);
  }
  float e0 = emb[((size_t)item << 6) + lane];
  float h = fmaxf(fmaf(agg, 0.125f, e0), 0.f);  // relu(agg01 + emb0)
  float h2 = tanhf(fmaf(aggp, 0.125f, h));      // tanh(agg01' + emb0')
  float dot = wave_sum(ue * h2);
  if (lane == 0) {
    out[b] = 1.f / (1.f + expf(-dot));
    out[bs + b] = 1.f / (1.f + expf(-(lab - 0.5f)));
  }
}

extern "C" void kernel_launch(void* const* d_in, const int* in_sizes, int n_in, void* d_out,
                              int out_size, void* d_ws, size_t ws_size, hipStream_t stream) {
  const int* ui = (const int*)d_in[0];
  const int* ii = (const int*)d_in[1];
  const float* emb = (const float*)d_in[2];
  const float* W = (const float*)d_in[3];
  const int* adjE = (const int*)d_in[4];
  const int* adjR = (const int*)d_in[5];
  const int* clicked = (const int*)d_in[6];
  const float* numc = (const float*)d_in[7];
  const float* labels = (const float*)d_in[8];

  int bs = in_sizes[0];
  int np1 = in_sizes[2] / 64;  // n_entity + 1 (= labels row stride = offset)
  int nuser = in_sizes[7];
  int hist = in_sizes[6] / nuser;

  // workspace layout (floats unless noted)
  float* user_emb = (float*)d_ws;                      // bs*64
  float* s0w = user_emb + (size_t)bs * 64;             // bs*8
  int* e1 = (int*)(s0w + (size_t)bs * 8);              // bs*8
  int* r1 = e1 + (size_t)bs * 8;                       // bs*8
  float* emb1 = (float*)(r1 + (size_t)bs * 8);         // bs*8*64
  float* emb1p = emb1 + (size_t)bs * 8 * 64;           // bs*8*64
  float* lab1p = emb1p + (size_t)bs * 8 * 64;          // bs*8
  float* sbuf = lab1p + (size_t)bs * 8;                // bs*8*64 (reused hop0/hop1)
  int* e2 = (int*)(sbuf + (size_t)bs * 8 * 64);        // bs*8*8
  int* r2 = e2 + (size_t)bs * 64;                      // bs*8*8
  float* w1 = (float*)(r2 + (size_t)bs * 64);          // bs*8*8

  int nt0 = bs;        // hop0 tasks
  int nt1 = bs * 8;    // hop1 tasks
  int nw_s0 = nt0 * 64;
  int nw_s1 = nt1 * 64;

  k_user<<<(nt0 + 3) / 4, 256, 0, stream>>>(ui, emb, clicked, numc, hist, user_emb, nt0);
  // hop0: score all 64 neighbors of each item, select top-8
  k_score<<<(nw_s0 + 3) / 4, 256, 0, stream>>>(ii, 0, emb, W, adjE, adjR, user_emb, sbuf,
                                               nw_s0);
  k_topsel<<<(nt0 + 3) / 4, 256, 0, stream>>>(ii, adjE, adjR, sbuf, e1, r1, s0w, nt0);
  // transform the selected hop-1 entities
  k_transform<<<(nt1 + 3) / 4, 256, 0, stream>>>(e1, r1, emb, W, emb1, nt1);
  // hop1: score all 64 neighbors of each selected entity, select top-8
  k_score<<<(nw_s1 + 3) / 4, 256, 0, stream>>>(e1, 3, emb, W, adjE, adjR, user_emb, sbuf,
                                               nw_s1);
  k_topsel<<<(nt1 + 3) / 4, 256, 0, stream>>>(e1, adjE, adjR, sbuf, e2, r2, w1, nt1);
  // hop1 aggregation (emb + labels)
  k_agg1<<<(nt1 + 3) / 4, 256, 0, stream>>>(ui, ii, emb, W, labels, np1, e1, e2, r2, w1,
                                            emb1, emb1p, lab1p, nt1);
  k_final<<<(nt0 + 3) / 4, 256, 0, stream>>>(ii, emb, user_emb, s0w, emb1, emb1p, lab1p,
                                             (float*)d_out, bs);
}

// Round 4
// 329.531 us; speedup vs baseline: 3.7862x; 3.7862x over previous
//
#include <hip/hip_runtime.h>
#include <math.h>

#define NEGV -9000000000000000.0f
#define NBLK 256
#define WPB 16  // waves per block
#define NTHR 1024

__device__ __forceinline__ float wave_sum(float v) {
#pragma unroll
  for (int m = 32; m; m >>= 1) v += __shfl_xor(v, m, 64);
  return v;
}

// Packed W in LDS: WL[r][k][e] (float4) = W[r][e][4k..4k+3].
// Lane e reads WL[(r*16+k)*64+e]: 64 lanes stride 16B contiguous ->
// conflict-free ds_read_b128.
struct LdsW {
  float4 w[8 * 16 * 64];  // 128 KB
  float xb[WPB][64];      // 4 KB, per-wave x staging
};

__device__ __forceinline__ void stage_W(float4* wl, const float* __restrict__ W) {
  const float4* Wg = (const float4*)W;
  for (int f = threadIdx.x; f < 8192; f += NTHR) {
    float4 v = Wg[f];  // coalesced global
    int r = f >> 10, e = (f >> 4) & 63, k = f & 15;
    wl[(((r << 4) + k) << 6) + e] = v;
  }
  __syncthreads();
}

// Stage x[0..63] into this wave's LDS buffer (wave-local ordering).
__device__ __forceinline__ void wave_stage(float* xbuf, int lane,
                                           const float* __restrict__ src) {
  __builtin_amdgcn_wave_barrier();
  xbuf[lane] = src[lane];
  __builtin_amdgcn_wave_barrier();
  asm volatile("s_waitcnt lgkmcnt(0)" ::: "memory");
  __builtin_amdgcn_wave_barrier();
}

// y_e = sum_d W[r][e=lane][d] * x[d]; identical fmaf chain order to prior rounds.
__device__ __forceinline__ float dotrow_lds(const float4* wl, int r, int lane,
                                            const float* xbuf) {
  const float4* wr = wl + ((r << 4) << 6) + lane;
  float acc = 0.f;
#pragma unroll
  for (int i = 0; i < 16; ++i) {
    float4 w = wr[i << 6];
    float4 x = *(const float4*)(xbuf + 4 * i);
    acc = fmaf(w.x, x.x, acc);
    acc = fmaf(w.y, x.y, acc);
    acc = fmaf(w.z, x.z, acc);
    acc = fmaf(w.w, x.w, acc);
  }
  return acc;
}

__device__ __forceinline__ float transform_lds(int nb, int r, int lane,
                                               const float* __restrict__ emb,
                                               const float4* wl, float* xbuf) {
  wave_stage(xbuf, lane, emb + ((size_t)nb << 6));
  return tanhf(dotrow_lds(wl, r, lane, xbuf));
}

// ---- user embedding: 4 waves/block, wave = one batch element ----
__global__ __launch_bounds__(256) void k_user(const int* __restrict__ ui,
                                              const float* __restrict__ emb,
                                              const int* __restrict__ clicked,
                                              const float* __restrict__ numc, int hist,
                                              float* __restrict__ user_emb, int ntask) {
  int w = threadIdx.x >> 6, lane = threadIdx.x & 63;
  int b = blockIdx.x * 4 + w;
  if (b >= ntask) return;
  int u = ui[b];
  float acc = 0.f;
  for (int h = 0; h < hist; ++h) {
    int it = clicked[u * hist + h];
    acc += emb[((size_t)it << 6) + lane];
  }
  user_emb[((size_t)b << 6) + lane] = acc * (1.0f / numc[u]);
}

// ---- score: persistent blocks, W in LDS, one wave per (task, neighbor) ----
__global__ __launch_bounds__(NTHR) void k_score_p(
    const int* __restrict__ eid_list, int shift, const float* __restrict__ emb,
    const float* __restrict__ W, const int* __restrict__ adjE,
    const int* __restrict__ adjR, const float* __restrict__ user_emb,
    float* __restrict__ sbuf, int nwave) {
  __shared__ LdsW S;
  stage_W(S.w, W);
  int w = threadIdx.x >> 6, lane = threadIdx.x & 63;
  int wid = blockIdx.x * WPB + w;
  int tot = gridDim.x * WPB;
  for (int gw = wid; gw < nwave; gw += tot) {
    int t = gw >> 6, n = gw & 63;
    int eid = eid_list[t];
    int b = t >> shift;
    int nb = adjE[((size_t)eid << 6) + n];
    int r = adjR[((size_t)eid << 6) + n];
    float u_e = user_emb[((size_t)b << 6) + lane];
    float y = transform_lds(nb, r, lane, emb, S.w, S.xb[w]);
    float s = wave_sum(u_e * y);
    if (lane == 0) sbuf[gw] = s * (1.0f / 64.0f);
  }
}

// ---- topsel: one wave per task (unchanged numerics) ----
__global__ __launch_bounds__(256) void k_topsel(const int* __restrict__ eid_list,
                                                const int* __restrict__ adjE,
                                                const int* __restrict__ adjR,
                                                const float* __restrict__ sbuf,
                                                int* __restrict__ e_sel,
                                                int* __restrict__ r_sel,
                                                float* __restrict__ wgt, int ntask) {
  int w = threadIdx.x >> 6, lane = threadIdx.x & 63;
  int t = blockIdx.x * 4 + w;
  if (t >= ntask) return;
  int eid = eid_list[t];
  float s_mine = sbuf[((size_t)t << 6) + lane];
  float sv = (s_mine == 0.0f) ? NEGV : s_mine;
  float mx = sv;
#pragma unroll
  for (int m = 32; m; m >>= 1) mx = fmaxf(mx, __shfl_xor(mx, m, 64));
  float p = expf(sv - mx);
  float Z = wave_sum(p);
  p /= Z;
  float v = p;
  int vi = lane;
  float selv[8];
  int seli[8];
#pragma unroll
  for (int j = 0; j < 8; ++j) {
    float bv = v;
    int bi = vi;
#pragma unroll
    for (int m = 1; m < 64; m <<= 1) {
      float ov = __shfl_xor(bv, m, 64);
      int oi = __shfl_xor(bi, m, 64);
      if (ov > bv || (ov == bv && oi < bi)) { bv = ov; bi = oi; }
    }
    selv[j] = bv;
    seli[j] = bi;
    if (lane == bi) v = -__builtin_inff();
  }
  float m8 = -__builtin_inff();
#pragma unroll
  for (int j = 0; j < 8; ++j) {
    float tt = (selv[j] == 0.f) ? NEGV : selv[j];
    selv[j] = tt;
    m8 = fmaxf(m8, tt);
  }
  float Z8 = 0.f;
#pragma unroll
  for (int j = 0; j < 8; ++j) {
    selv[j] = expf(selv[j] - m8);
    Z8 += selv[j];
  }
  int nbr = adjE[((size_t)eid << 6) + lane];
  int rel = adjR[((size_t)eid << 6) + lane];
#pragma unroll
  for (int j = 0; j < 8; ++j) {
    int nb = __shfl(nbr, seli[j], 64);
    int rr = __shfl(rel, seli[j], 64);
    if (lane == 0) {
      e_sel[t * 8 + j] = nb;
      r_sel[t * 8 + j] = rr;
      wgt[t * 8 + j] = selv[j] / Z8;
    }
  }
}

// ---- transform selected entities: persistent, W in LDS ----
__global__ __launch_bounds__(NTHR) void k_transform_p(const int* __restrict__ e_sel,
                                                      const int* __restrict__ r_sel,
                                                      const float* __restrict__ emb,
                                                      const float* __restrict__ W,
                                                      float* __restrict__ out, int nwave) {
  __shared__ LdsW S;
  stage_W(S.w, W);
  int w = threadIdx.x >> 6, lane = threadIdx.x & 63;
  int wid = blockIdx.x * WPB + w;
  int tot = gridDim.x * WPB;
  for (int gw = wid; gw < nwave; gw += tot) {
    float y = transform_lds(e_sel[gw], r_sel[gw], lane, emb, S.w, S.xb[w]);
    out[((size_t)gw << 6) + lane] = y;
  }
}

// ---- hop1 aggregation (emb + labels): persistent, W in LDS ----
__global__ __launch_bounds__(NTHR) void k_agg1_p(
    const int* __restrict__ ui, const int* __restrict__ ii, const float* __restrict__ emb,
    const float* __restrict__ W, const float* __restrict__ labels, int np1,
    const int* __restrict__ e1, const int* __restrict__ e2, const int* __restrict__ r2,
    const float* __restrict__ w1, const float* __restrict__ emb1,
    float* __restrict__ emb1p, float* __restrict__ lab1p, int ntask) {
  __shared__ LdsW S;
  stage_W(S.w, W);
  int w = threadIdx.x >> 6, lane = threadIdx.x & 63;
  int wid = blockIdx.x * WPB + w;
  int tot = gridDim.x * WPB;
  for (int bj = wid; bj < ntask; bj += tot) {
    int b = bj >> 3;
    int u = ui[b];
    int item = ii[b];
    int eid = e1[bj];
    float agg = 0.f, labagg = 0.f;
#pragma unroll
    for (int k = 0; k < 8; ++k) {
      int nb = e2[bj * 8 + k];
      int r = r2[bj * 8 + k];
      float wk = w1[bj * 8 + k];
      float y = transform_lds(nb, r, lane, emb, S.w, S.xb[w]);
      agg = fmaf(wk, y, agg);
      float raw2 = labels[(size_t)u * np1 + nb];
      float lab2 = (nb != item) ? raw2 : 0.5f;
      labagg = fmaf(wk, lab2, labagg);
    }
    float base = emb1[((size_t)bj << 6) + lane];
    emb1p[((size_t)bj << 6) + lane] = fmaxf(fmaf(agg, 0.125f, base), 0.f);
    if (lane == 0) {
      float raw1 = labels[(size_t)u * np1 + eid];
      bool hm = (eid != item);
      float l1 = hm ? raw1 : 0.5f;
      bool reset1 = (raw1 != 0.5f) && hm;
      lab1p[bj] = reset1 ? l1 : labagg;
    }
  }
}

__global__ __launch_bounds__(256) void k_final(const int* __restrict__ ii,
                                               const float* __restrict__ emb,
                                               const float* __restrict__ user_emb,
                                               const float* __restrict__ s0,
                                               const float* __restrict__ emb1,
                                               const float* __restrict__ emb1p,
                                               const float* __restrict__ lab1p,
                                               float* __restrict__ out, int bs) {
  int w = threadIdx.x >> 6, lane = threadIdx.x & 63;
  int b = blockIdx.x * 4 + w;
  if (b >= bs) return;
  int item = ii[b];
  float ue = user_emb[((size_t)b << 6) + lane];
  float agg = 0.f, aggp = 0.f, lab = 0.f;
#pragma unroll
  for (int j = 0; j < 8; ++j) {
    float s = s0[b * 8 + j];
    agg = fmaf(s, emb1[(((size_t)b * 8 + j) << 6) + lane], agg);
    aggp = fmaf(s, emb1p[(((size_t)b * 8 + j) << 6) + lane], aggp);
    lab = fmaf(s, lab1p[b * 8 + j], lab);
  }
  float e0 = emb[((size_t)item << 6) + lane];
  float h = fmaxf(fmaf(agg, 0.125f, e0), 0.f);  // relu(agg01 + emb0)
  float h2 = tanhf(fmaf(aggp, 0.125f, h));      // tanh(agg01' + emb0')
  float dot = wave_sum(ue * h2);
  if (lane == 0) {
    out[b] = 1.f / (1.f + expf(-dot));
    out[bs + b] = 1.f / (1.f + expf(-(lab - 0.5f)));
  }
}

extern "C" void kernel_launch(void* const* d_in, const int* in_sizes, int n_in, void* d_out,
                              int out_size, void* d_ws, size_t ws_size, hipStream_t stream) {
  const int* ui = (const int*)d_in[0];
  const int* ii = (const int*)d_in[1];
  const float* emb = (const float*)d_in[2];
  const float* W = (const float*)d_in[3];
  const int* adjE = (const int*)d_in[4];
  const int* adjR = (const int*)d_in[5];
  const int* clicked = (const int*)d_in[6];
  const float* numc = (const float*)d_in[7];
  const float* labels = (const float*)d_in[8];

  int bs = in_sizes[0];
  int np1 = in_sizes[2] / 64;  // n_entity + 1 (= labels row stride = offset)
  int nuser = in_sizes[7];
  int hist = in_sizes[6] / nuser;

  // workspace layout
  float* user_emb = (float*)d_ws;                  // bs*64
  float* s0w = user_emb + (size_t)bs * 64;         // bs*8
  int* e1 = (int*)(s0w + (size_t)bs * 8);          // bs*8
  int* r1 = e1 + (size_t)bs * 8;                   // bs*8
  float* emb1 = (float*)(r1 + (size_t)bs * 8);     // bs*8*64
  float* emb1p = emb1 + (size_t)bs * 8 * 64;       // bs*8*64
  float* lab1p = emb1p + (size_t)bs * 8 * 64;      // bs*8
  float* sbuf = lab1p + (size_t)bs * 8;            // bs*8*64 (reused hop0/hop1)
  int* e2 = (int*)(sbuf + (size_t)bs * 8 * 64);    // bs*8*8
  int* r2 = e2 + (size_t)bs * 64;                  // bs*8*8
  float* w1 = (float*)(r2 + (size_t)bs * 64);      // bs*8*8

  int nt0 = bs;      // hop0 tasks
  int nt1 = bs * 8;  // hop1 tasks
  int nw_s0 = nt0 * 64;
  int nw_s1 = nt1 * 64;

  k_user<<<(nt0 + 3) / 4, 256, 0, stream>>>(ui, emb, clicked, numc, hist, user_emb, nt0);
  // hop0: score all 64 neighbors of each item, select top-8
  k_score_p<<<NBLK, NTHR, 0, stream>>>(ii, 0, emb, W, adjE, adjR, user_emb, sbuf, nw_s0);
  k_topsel<<<(nt0 + 3) / 4, 256, 0, stream>>>(ii, adjE, adjR, sbuf, e1, r1, s0w, nt0);
  // transform the selected hop-1 entities
  k_transform_p<<<NBLK, NTHR, 0, stream>>>(e1, r1, emb, W, emb1, nt1);
  // hop1: score all 64 neighbors of each selected entity, select top-8
  k_score_p<<<NBLK, NTHR, 0, stream>>>(e1, 3, emb, W, adjE, adjR, user_emb, sbuf, nw_s1);
  k_topsel<<<(nt1 + 3) / 4, 256, 0, stream>>>(e1, adjE, adjR, sbuf, e2, r2, w1, nt1);
  // hop1 aggregation (emb + labels)
  k_agg1_p<<<NBLK, NTHR, 0, stream>>>(ui, ii, emb, W, labels, np1, e1, e2, r2, w1, emb1,
                                      emb1p, lab1p, nt1);
  k_final<<<(nt0 + 3) / 4, 256, 0, stream>>>(ii, emb, user_emb, s0w, emb1, emb1p, lab1p,
                                             (float*)d_out, bs);
}

// Round 5
// 282.966 us; speedup vs baseline: 4.4093x; 1.1646x over previous
//
#include <hip/hip_runtime.h>
#include <math.h>

#define NEGV -9000000000000000.0f
#define NBLK 256
#define WPB 16  // waves per block
#define NTHR 1024

__device__ __forceinline__ float wave_sum(float v) {
#pragma unroll
  for (int m = 32; m; m >>= 1) v += __shfl_xor(v, m, 64);
  return v;
}

// Packed W in LDS: WL[r][k][e] (float4) = W[r][e][4k..4k+3].
// Lane e reads WL[(r*16+k)*64+e]: 64 lanes stride 16B contiguous ->
// conflict-free ds_read_b128.
struct LdsW {
  float4 w[8 * 16 * 64];  // 128 KB
  float xb[WPB][64];      // 4 KB, per-wave x staging
};

__device__ __forceinline__ void stage_W(float4* wl, const float* __restrict__ W) {
  const float4* Wg = (const float4*)W;
  for (int f = threadIdx.x; f < 8192; f += NTHR) {
    float4 v = Wg[f];  // coalesced global
    int r = f >> 10, e = (f >> 4) & 63, k = f & 15;
    wl[(((r << 4) + k) << 6) + e] = v;
  }
  __syncthreads();
}

// Stage x[0..63] into this wave's LDS buffer (wave-local ordering).
__device__ __forceinline__ void wave_stage(float* xbuf, int lane,
                                           const float* __restrict__ src) {
  __builtin_amdgcn_wave_barrier();
  xbuf[lane] = src[lane];
  __builtin_amdgcn_wave_barrier();
  asm volatile("s_waitcnt lgkmcnt(0)" ::: "memory");
  __builtin_amdgcn_wave_barrier();
}

// y_e = sum_d W[r][e=lane][d] * x[d]; identical fmaf chain order to prior rounds.
__device__ __forceinline__ float dotrow_lds(const float4* wl, int r, int lane,
                                            const float* xbuf) {
  const float4* wr = wl + ((r << 4) << 6) + lane;
  float acc = 0.f;
#pragma unroll
  for (int i = 0; i < 16; ++i) {
    float4 w = wr[i << 6];
    float4 x = *(const float4*)(xbuf + 4 * i);
    acc = fmaf(w.x, x.x, acc);
    acc = fmaf(w.y, x.y, acc);
    acc = fmaf(w.z, x.z, acc);
    acc = fmaf(w.w, x.w, acc);
  }
  return acc;
}

__device__ __forceinline__ float transform_lds(int nb, int r, int lane,
                                               const float* __restrict__ emb,
                                               const float4* wl, float* xbuf) {
  wave_stage(xbuf, lane, emb + ((size_t)nb << 6));
  return tanhf(dotrow_lds(wl, r, lane, xbuf));
}

// ---- user embedding: 4 waves/block, wave = one batch element ----
__global__ __launch_bounds__(256) void k_user(const int* __restrict__ ui,
                                              const float* __restrict__ emb,
                                              const int* __restrict__ clicked,
                                              const float* __restrict__ numc, int hist,
                                              float* __restrict__ user_emb, int ntask) {
  int w = threadIdx.x >> 6, lane = threadIdx.x & 63;
  int b = blockIdx.x * 4 + w;
  if (b >= ntask) return;
  int u = ui[b];
  float acc = 0.f;
  for (int h = 0; h < hist; ++h) {
    int it = clicked[u * hist + h];
    acc += emb[((size_t)it << 6) + lane];
  }
  user_emb[((size_t)b << 6) + lane] = acc * (1.0f / numc[u]);
}

// ---- fused score+topsel: one wave per task, neighbors grouped by relation.
// W row for the current relation is held in registers (wreg) and reused across
// the group; per-neighbor cost = x stage + bit-exact fmaf chain. Score order
// across neighbors doesn't affect numerics (independent chains).
__global__ __launch_bounds__(NTHR) void k_hop_fused(
    const int* __restrict__ eid_list, int shift, const float* __restrict__ emb,
    const float* __restrict__ W, const int* __restrict__ adjE,
    const int* __restrict__ adjR, const float* __restrict__ user_emb,
    int* __restrict__ e_sel, int* __restrict__ r_sel, float* __restrict__ wgt,
    int ntask) {
  __shared__ LdsW S;
  stage_W(S.w, W);
  int w = threadIdx.x >> 6, lane = threadIdx.x & 63;
  float* xbuf = S.xb[w];
  int wid = blockIdx.x * WPB + w;
  int tot = gridDim.x * WPB;
  for (int t = wid; t < ntask; t += tot) {
    int eid = eid_list[t];
    int b = t >> shift;
    int nbr = adjE[((size_t)eid << 6) + lane];
    int rel = adjR[((size_t)eid << 6) + lane];
    float u_e = user_emb[((size_t)b << 6) + lane];
    // rank of this lane in relation-sorted order (stable within relation)
    int myrank = 0, basec = 0;
    unsigned long long ltmask = (1ull << lane) - 1ull;
#pragma unroll
    for (int rr = 0; rr < 8; ++rr) {
      unsigned long long m = __ballot(rel == rr);
      if (rel == rr) myrank = basec + (int)__popcll(m & ltmask);
      basec += (int)__popcll(m);
    }
    // order[k] = original neighbor index of k-th sorted element (push-permute)
    int order = __builtin_amdgcn_ds_permute(myrank << 2, lane);
    int srt_nb = __shfl(nbr, order, 64);  // neighbor entity of k-th sorted
    int srt_r = __shfl(rel, order, 64);   // relation of k-th sorted
    int nb0 = __shfl(srt_nb, 0, 64);
    float xv = emb[((size_t)nb0 << 6) + lane];  // prefetch first x
    float4 wreg[16];
    int rcur = -1;
    float s_mine = 0.f;
    for (int i = 0; i < 64; ++i) {
      int n = __shfl(order, i, 64);
      int r = __builtin_amdgcn_readfirstlane(__shfl(srt_r, i, 64));
      if (r != rcur) {  // reload W row into registers (~8x per task)
        const float4* wr = S.w + (r << 10) + lane;
#pragma unroll
        for (int k = 0; k < 16; ++k) wreg[k] = wr[k << 6];
        rcur = r;
      }
      float xnext = 0.f;
      if (i < 63) {  // issue next x load before the fence; stays in flight
        int nb1 = __shfl(srt_nb, i + 1, 64);
        xnext = emb[((size_t)nb1 << 6) + lane];
      }
      __builtin_amdgcn_wave_barrier();
      xbuf[lane] = xv;
      __builtin_amdgcn_wave_barrier();
      asm volatile("s_waitcnt lgkmcnt(0)" ::: "memory");
      __builtin_amdgcn_wave_barrier();
      float acc = 0.f;
#pragma unroll
      for (int k = 0; k < 16; ++k) {
        float4 x = *(const float4*)(xbuf + 4 * k);
        acc = fmaf(wreg[k].x, x.x, acc);
        acc = fmaf(wreg[k].y, x.y, acc);
        acc = fmaf(wreg[k].z, x.z, acc);
        acc = fmaf(wreg[k].w, x.w, acc);
      }
      float y = tanhf(acc);
      float totv = wave_sum(u_e * y);
      if (lane == n) s_mine = totv * (1.0f / 64.0f);
      xv = xnext;
    }
    // ---- topsel (numerics identical to prior rounds) ----
    float sv = (s_mine == 0.0f) ? NEGV : s_mine;
    float mx = sv;
#pragma unroll
    for (int m = 32; m; m >>= 1) mx = fmaxf(mx, __shfl_xor(mx, m, 64));
    float p = expf(sv - mx);
    float Z = wave_sum(p);
    p /= Z;
    float v = p;
    int vi = lane;
    float selv[8];
    int seli[8];
#pragma unroll
    for (int j = 0; j < 8; ++j) {
      float bv = v;
      int bi = vi;
#pragma unroll
      for (int m = 1; m < 64; m <<= 1) {
        float ov = __shfl_xor(bv, m, 64);
        int oi = __shfl_xor(bi, m, 64);
        if (ov > bv || (ov == bv && oi < bi)) { bv = ov; bi = oi; }
      }
      selv[j] = bv;
      seli[j] = bi;
      if (lane == bi) v = -__builtin_inff();
    }
    float m8 = -__builtin_inff();
#pragma unroll
    for (int j = 0; j < 8; ++j) {
      float tt = (selv[j] == 0.f) ? NEGV : selv[j];
      selv[j] = tt;
      m8 = fmaxf(m8, tt);
    }
    float Z8 = 0.f;
#pragma unroll
    for (int j = 0; j < 8; ++j) {
      selv[j] = expf(selv[j] - m8);
      Z8 += selv[j];
    }
#pragma unroll
    for (int j = 0; j < 8; ++j) {
      int nb = __shfl(nbr, seli[j], 64);
      int rr = __shfl(rel, seli[j], 64);
      if (lane == 0) {
        e_sel[t * 8 + j] = nb;
        r_sel[t * 8 + j] = rr;
        wgt[t * 8 + j] = selv[j] / Z8;
      }
    }
  }
}

// ---- transform selected entities: persistent, W in LDS ----
__global__ __launch_bounds__(NTHR) void k_transform_p(const int* __restrict__ e_sel,
                                                      const int* __restrict__ r_sel,
                                                      const float* __restrict__ emb,
                                                      const float* __restrict__ W,
                                                      float* __restrict__ out, int nwave) {
  __shared__ LdsW S;
  stage_W(S.w, W);
  int w = threadIdx.x >> 6, lane = threadIdx.x & 63;
  int wid = blockIdx.x * WPB + w;
  int tot = gridDim.x * WPB;
  for (int gw = wid; gw < nwave; gw += tot) {
    float y = transform_lds(e_sel[gw], r_sel[gw], lane, emb, S.w, S.xb[w]);
    out[((size_t)gw << 6) + lane] = y;
  }
}

// ---- hop1 aggregation (emb + labels): persistent, W in LDS ----
__global__ __launch_bounds__(NTHR) void k_agg1_p(
    const int* __restrict__ ui, const int* __restrict__ ii, const float* __restrict__ emb,
    const float* __restrict__ W, const float* __restrict__ labels, int np1,
    const int* __restrict__ e1, const int* __restrict__ e2, const int* __restrict__ r2,
    const float* __restrict__ w1, const float* __restrict__ emb1,
    float* __restrict__ emb1p, float* __restrict__ lab1p, int ntask) {
  __shared__ LdsW S;
  stage_W(S.w, W);
  int w = threadIdx.x >> 6, lane = threadIdx.x & 63;
  int wid = blockIdx.x * WPB + w;
  int tot = gridDim.x * WPB;
  for (int bj = wid; bj < ntask; bj += tot) {
    int b = bj >> 3;
    int u = ui[b];
    int item = ii[b];
    int eid = e1[bj];
    float agg = 0.f, labagg = 0.f;
#pragma unroll
    for (int k = 0; k < 8; ++k) {
      int nb = e2[bj * 8 + k];
      int r = r2[bj * 8 + k];
      float wk = w1[bj * 8 + k];
      float y = transform_lds(nb, r, lane, emb, S.w, S.xb[w]);
      agg = fmaf(wk, y, agg);
      float raw2 = labels[(size_t)u * np1 + nb];
      float lab2 = (nb != item) ? raw2 : 0.5f;
      labagg = fmaf(wk, lab2, labagg);
    }
    float base = emb1[((size_t)bj << 6) + lane];
    emb1p[((size_t)bj << 6) + lane] = fmaxf(fmaf(agg, 0.125f, base), 0.f);
    if (lane == 0) {
      float raw1 = labels[(size_t)u * np1 + eid];
      bool hm = (eid != item);
      float l1 = hm ? raw1 : 0.5f;
      bool reset1 = (raw1 != 0.5f) && hm;
      lab1p[bj] = reset1 ? l1 : labagg;
    }
  }
}

__global__ __launch_bounds__(256) void k_final(const int* __restrict__ ii,
                                               const float* __restrict__ emb,
                                               const float* __restrict__ user_emb,
                                               const float* __restrict__ s0,
                                               const float* __restrict__ emb1,
                                               const float* __restrict__ emb1p,
                                               const float* __restrict__ lab1p,
                                               float* __restrict__ out, int bs) {
  int w = threadIdx.x >> 6, lane = threadIdx.x & 63;
  int b = blockIdx.x * 4 + w;
  if (b >= bs) return;
  int item = ii[b];
  float ue = user_emb[((size_t)b << 6) + lane];
  float agg = 0.f, aggp = 0.f, lab = 0.f;
#pragma unroll
  for (int j = 0; j < 8; ++j) {
    float s = s0[b * 8 + j];
    agg = fmaf(s, emb1[(((size_t)b * 8 + j) << 6) + lane], agg);
    aggp = fmaf(s, emb1p[(((size_t)b * 8 + j) << 6) + lane], aggp);
    lab = fmaf(s, lab1p[b * 8 + j], lab);
  }
  float e0 = emb[((size_t)item << 6) + lane];
  float h = fmaxf(fmaf(agg, 0.125f, e0), 0.f);  // relu(agg01 + emb0)
  float h2 = tanhf(fmaf(aggp, 0.125f, h));      // tanh(agg01' + emb0')
  float dot = wave_sum(ue * h2);
  if (lane == 0) {
    out[b] = 1.f / (1.f + expf(-dot));
    out[bs + b] = 1.f / (1.f + expf(-(lab - 0.5f)));
  }
}

extern "C" void kernel_launch(void* const* d_in, const int* in_sizes, int n_in, void* d_out,
                              int out_size, void* d_ws, size_t ws_size, hipStream_t stream) {
  const int* ui = (const int*)d_in[0];
  const int* ii = (const int*)d_in[1];
  const float* emb = (const float*)d_in[2];
  const float* W = (const float*)d_in[3];
  const int* adjE = (const int*)d_in[4];
  const int* adjR = (const int*)d_in[5];
  const int* clicked = (const int*)d_in[6];
  const float* numc = (const float*)d_in[7];
  const float* labels = (const float*)d_in[8];

  int bs = in_sizes[0];
  int np1 = in_sizes[2] / 64;  // n_entity + 1 (= labels row stride = offset)
  int nuser = in_sizes[7];
  int hist = in_sizes[6] / nuser;

  // workspace layout
  float* user_emb = (float*)d_ws;                // bs*64
  float* s0w = user_emb + (size_t)bs * 64;       // bs*8
  int* e1 = (int*)(s0w + (size_t)bs * 8);        // bs*8
  int* r1 = e1 + (size_t)bs * 8;                 // bs*8
  float* emb1 = (float*)(r1 + (size_t)bs * 8);   // bs*8*64
  float* emb1p = emb1 + (size_t)bs * 8 * 64;     // bs*8*64
  float* lab1p = emb1p + (size_t)bs * 8 * 64;    // bs*8
  int* e2 = (int*)(lab1p + (size_t)bs * 8);      // bs*8*8
  int* r2 = e2 + (size_t)bs * 64;                // bs*8*8
  float* w1 = (float*)(r2 + (size_t)bs * 64);    // bs*8*8

  int nt0 = bs;      // hop0 tasks
  int nt1 = bs * 8;  // hop1 tasks

  k_user<<<(nt0 + 3) / 4, 256, 0, stream>>>(ui, emb, clicked, numc, hist, user_emb, nt0);
  // hop0: score 64 neighbors of each item + select top-8 (fused)
  k_hop_fused<<<NBLK, NTHR, 0, stream>>>(ii, 0, emb, W, adjE, adjR, user_emb, e1, r1, s0w,
                                         nt0);
  // transform the selected hop-1 entities
  k_transform_p<<<NBLK, NTHR, 0, stream>>>(e1, r1, emb, W, emb1, nt1);
  // hop1: score 64 neighbors of each selected entity + select top-8 (fused)
  k_hop_fused<<<NBLK, NTHR, 0, stream>>>(e1, 3, emb, W, adjE, adjR, user_emb, e2, r2, w1,
                                         nt1);
  // hop1 aggregation (emb + labels)
  k_agg1_p<<<NBLK, NTHR, 0, stream>>>(ui, ii, emb, W, labels, np1, e1, e2, r2, w1, emb1,
                                      emb1p, lab1p, nt1);
  k_final<<<(nt0 + 3) / 4, 256, 0, stream>>>(ii, emb, user_emb, s0w, emb1, emb1p, lab1p,
                                             (float*)d_out, bs);
}